// Round 2
// baseline (10092.549 us; speedup 1.0000x reference)
//
#include <hip/hip_runtime.h>
#include <hip/hip_bf16.h>

// Problem constants
#define BB 2
#define TT 2048
#define DD 512
#define HH 8
#define HS 64
#define VV 32000
#define FF 2048   // 4*D
#define MM (BB*TT) // 4096

// ---------------------------------------------------------------------------
// Embedding: x[m][d] = tok_emb[idx[m]][d] + pos_emb[t][d]
// ---------------------------------------------------------------------------
__global__ __launch_bounds__(256) void embed_kernel(
    const int* __restrict__ idx, const float* __restrict__ tok,
    const float* __restrict__ pos, float* __restrict__ x)
{
    int i = blockIdx.x * 256 + threadIdx.x;   // over MM*DD
    int m = i >> 9;          // /512
    int d = i & 511;
    int t = m & (TT - 1);
    x[i] = tok[(size_t)idx[m] * DD + d] + pos[(size_t)t * DD + d];
}

// ---------------------------------------------------------------------------
// LayerNorm: one block (256 thr) per row of 512
// ---------------------------------------------------------------------------
__global__ __launch_bounds__(256) void ln_kernel(
    const float* __restrict__ x, const float* __restrict__ g,
    const float* __restrict__ b, float* __restrict__ out)
{
    int row = blockIdx.x;
    int tid = threadIdx.x;
    const float* xr = x + (size_t)row * DD;
    float v0 = xr[tid], v1 = xr[tid + 256];
    __shared__ float rs[256];
    rs[tid] = v0 + v1;
    __syncthreads();
    for (int off = 128; off > 0; off >>= 1) {
        if (tid < off) rs[tid] += rs[tid + off];
        __syncthreads();
    }
    float mean = rs[0] * (1.0f / DD);
    __syncthreads();
    float d0 = v0 - mean, d1 = v1 - mean;
    rs[tid] = d0 * d0 + d1 * d1;
    __syncthreads();
    for (int off = 128; off > 0; off >>= 1) {
        if (tid < off) rs[tid] += rs[tid + off];
        __syncthreads();
    }
    float rstd = rsqrtf(rs[0] * (1.0f / DD) + 1e-5f);
    float* o = out + (size_t)row * DD;
    o[tid]       = d0 * rstd * g[tid]       + b[tid];
    o[tid + 256] = d1 * rstd * g[tid + 256] + b[tid + 256];
}

// ---------------------------------------------------------------------------
// GEMM: C[M,N] = A[M,K] * W[K,N] + bias (+ residual) (+ relu), all fp32.
// 64x64 tile, BK=16, 256 threads, 4x4 register tile per thread.
// ---------------------------------------------------------------------------
#define BM 64
#define BN 64
#define BK 16
#define LDSP 68   // padded leading dim (multiple of 4 -> float4-aligned rows)

__global__ __launch_bounds__(256) void gemm_kernel(
    const float* __restrict__ A, const float* __restrict__ W,
    const float* __restrict__ bias, float* __restrict__ C,
    const float* __restrict__ res,
    int M, int N, int K, int relu)
{
    __shared__ float As[BK][LDSP];
    __shared__ float Bs[BK][LDSP];
    const int tid = threadIdx.x;
    const int row0 = blockIdx.y * BM;
    const int col0 = blockIdx.x * BN;
    const int tx = tid & 15, ty = tid >> 4;

    const int ar = tid >> 2, ac = (tid & 3) << 2;   // A tile: 64 rows x 16 cols
    const int wr = tid >> 4, wc = (tid & 15) << 2;  // W tile: 16 rows x 64 cols

    float acc[4][4] = {};

    for (int k0 = 0; k0 < K; k0 += BK) {
        float4 av = *(const float4*)(A + (size_t)(row0 + ar) * K + k0 + ac);
        As[ac + 0][ar] = av.x;
        As[ac + 1][ar] = av.y;
        As[ac + 2][ar] = av.z;
        As[ac + 3][ar] = av.w;
        float4 wv = *(const float4*)(W + (size_t)(k0 + wr) * N + col0 + wc);
        Bs[wr][wc + 0] = wv.x;
        Bs[wr][wc + 1] = wv.y;
        Bs[wr][wc + 2] = wv.z;
        Bs[wr][wc + 3] = wv.w;
        __syncthreads();
#pragma unroll
        for (int k = 0; k < BK; ++k) {
            float4 a = *(const float4*)&As[k][ty << 2];
            float4 bv = *(const float4*)&Bs[k][tx << 2];
            float aa[4] = {a.x, a.y, a.z, a.w};
            float bb[4] = {bv.x, bv.y, bv.z, bv.w};
#pragma unroll
            for (int i = 0; i < 4; ++i)
#pragma unroll
                for (int j = 0; j < 4; ++j)
                    acc[i][j] = fmaf(aa[i], bb[j], acc[i][j]);
        }
        __syncthreads();
    }

    // epilogue
#pragma unroll
    for (int i = 0; i < 4; ++i) {
        int r = row0 + (ty << 2) + i;
        size_t base = (size_t)r * N + col0 + (tx << 2);
#pragma unroll
        for (int j = 0; j < 4; ++j) {
            float v = acc[i][j];
            if (bias) v += bias[col0 + (tx << 2) + j];
            if (relu) v = fmaxf(v, 0.0f);
            if (res)  v += res[base + j];
            C[base + j] = v;
        }
    }
}

// ---------------------------------------------------------------------------
// Attention: one block (256 thr) per (b, h, t) query row. Two-pass softmax,
// scores staged in LDS (<= 2048 floats).
// ---------------------------------------------------------------------------
__global__ __launch_bounds__(256) void attn_kernel(
    const float* __restrict__ qf, const float* __restrict__ kf,
    const float* __restrict__ vf, float* __restrict__ att)
{
    const int t = blockIdx.x, h = blockIdx.y, b = blockIdx.z;
    const int tid = threadIdx.x;
    __shared__ float qs[HS];
    __shared__ float sc[TT];
    __shared__ float red[256];
    __shared__ float part[4][HS];
    const float scale = 0.044194173824159216f; // 512^-0.5

    const size_t baseq = ((size_t)(b * TT + t) * DD) + h * HS;
    if (tid < HS) qs[tid] = qf[baseq + tid];
    __syncthreads();

    // pass 1: scores for s <= t
    float lmax = -INFINITY;
    for (int s = tid; s <= t; s += 256) {
        const float* kp = kf + ((size_t)(b * TT + s) * DD) + h * HS;
        float dot = 0.0f;
#pragma unroll
        for (int d = 0; d < HS; d += 4) {
            float4 kv = *(const float4*)(kp + d);
            dot = fmaf(qs[d], kv.x, dot);
            dot = fmaf(qs[d + 1], kv.y, dot);
            dot = fmaf(qs[d + 2], kv.z, dot);
            dot = fmaf(qs[d + 3], kv.w, dot);
        }
        dot *= scale;
        sc[s] = dot;
        lmax = fmaxf(lmax, dot);
    }
    red[tid] = lmax;
    __syncthreads();
    for (int off = 128; off > 0; off >>= 1) {
        if (tid < off) red[tid] = fmaxf(red[tid], red[tid + off]);
        __syncthreads();
    }
    float m = red[0];
    __syncthreads();

    float lsum = 0.0f;
    for (int s = tid; s <= t; s += 256) {
        float e = __expf(sc[s] - m);
        sc[s] = e;
        lsum += e;
    }
    red[tid] = lsum;
    __syncthreads();
    for (int off = 128; off > 0; off >>= 1) {
        if (tid < off) red[tid] += red[tid + off];
        __syncthreads();
    }
    float linv = 1.0f / red[0];
    __syncthreads();

    // pass 2: out[d] = sum_s w[s] * v[s][d]
    const int g = tid >> 6, lane = tid & 63;
    float acc = 0.0f;
    for (int s = g; s <= t; s += 4) {
        acc = fmaf(sc[s], vf[((size_t)(b * TT + s) * DD) + h * HS + lane], acc);
    }
    part[g][lane] = acc;
    __syncthreads();
    if (g == 0) {
        float tot = (part[0][lane] + part[1][lane] + part[2][lane] + part[3][lane]) * linv;
        att[baseq + lane] = tot;
    }
}

// ---------------------------------------------------------------------------
// Launch
// ---------------------------------------------------------------------------
extern "C" void kernel_launch(void* const* d_in, const int* in_sizes, int n_in,
                              void* d_out, int out_size, void* d_ws, size_t ws_size,
                              hipStream_t stream) {
    const int*   idx    = (const int*)  d_in[0];
    const float* tok    = (const float*)d_in[1];
    const float* pos    = (const float*)d_in[2];
    const float* ln1_g  = (const float*)d_in[3];
    const float* ln1_b  = (const float*)d_in[4];
    const float* Wq     = (const float*)d_in[5];
    const float* Wk     = (const float*)d_in[6];
    const float* Wv     = (const float*)d_in[7];
    const float* Wo     = (const float*)d_in[8];
    const float* bo     = (const float*)d_in[9];
    const float* ln2_g  = (const float*)d_in[10];
    const float* ln2_b  = (const float*)d_in[11];
    const float* W1     = (const float*)d_in[12];
    const float* b1     = (const float*)d_in[13];
    const float* W2     = (const float*)d_in[14];
    const float* b2     = (const float*)d_in[15];
    const float* lm_W   = (const float*)d_in[16];
    const float* lm_b   = (const float*)d_in[17];
    float* out = (float*)d_out;

    // workspace layout (floats): x (2M), h (2M), big (8M: q/k/v then ffn-mid)
    float* ws  = (float*)d_ws;
    float* xf  = ws;
    float* hf  = ws + (1u << 21);
    float* big = ws + (2u << 21);
    float* qf  = big;
    float* kf  = big + (1u << 21);
    float* vf  = big + (2u << 21);
    float* mid = big;

    dim3 blk(256);
    embed_kernel<<<dim3((MM * DD) / 256), blk, 0, stream>>>(idx, tok, pos, xf);

    for (int l = 0; l < 4; ++l) {
        ln_kernel<<<dim3(MM), blk, 0, stream>>>(xf, ln1_g + l * DD, ln1_b + l * DD, hf);
        gemm_kernel<<<dim3(DD / BN, MM / BM), blk, 0, stream>>>(
            hf, Wq + (size_t)l * DD * DD, nullptr, qf, nullptr, MM, DD, DD, 0);
        gemm_kernel<<<dim3(DD / BN, MM / BM), blk, 0, stream>>>(
            hf, Wk + (size_t)l * DD * DD, nullptr, kf, nullptr, MM, DD, DD, 0);
        gemm_kernel<<<dim3(DD / BN, MM / BM), blk, 0, stream>>>(
            hf, Wv + (size_t)l * DD * DD, nullptr, vf, nullptr, MM, DD, DD, 0);
        attn_kernel<<<dim3(TT, HH, BB), blk, 0, stream>>>(qf, kf, vf, hf);
        gemm_kernel<<<dim3(DD / BN, MM / BM), blk, 0, stream>>>(
            hf, Wo + (size_t)l * DD * DD, bo + l * DD, xf, xf, MM, DD, DD, 0);
        ln_kernel<<<dim3(MM), blk, 0, stream>>>(xf, ln2_g + l * DD, ln2_b + l * DD, hf);
        gemm_kernel<<<dim3(FF / BN, MM / BM), blk, 0, stream>>>(
            hf, W1 + (size_t)l * DD * FF, b1 + l * FF, mid, nullptr, MM, FF, DD, 1);
        gemm_kernel<<<dim3(DD / BN, MM / BM), blk, 0, stream>>>(
            mid, W2 + (size_t)l * FF * DD, b2 + l * DD, xf, xf, MM, DD, FF, 0);
    }
    gemm_kernel<<<dim3(VV / BN, MM / BM), blk, 0, stream>>>(
        xf, lm_W, lm_b, out, nullptr, MM, VV, DD, 0);
}